// Round 8
// baseline (16848.331 us; speedup 1.0000x reference)
//
#include <hip/hip_runtime.h>

// Persistent-kernel LSTM autoencoder for MI355X — round 8.
// Round-6 kernel with the VGPR cap fixed: __launch_bounds__(512, 1)
// (1 block/CU -> 8 waves/CU -> 2 waves/SIMD -> 256-VGPR budget; round 6's
// (512,2) capped at 128 and spilled the 176-reg weight set to scratch).
// Topology: 8 groups x 2 WGs x 512 thr; group g = blocks {g, g+8} (same
// XCD under round-robin dispatch — validated by FETCH collapse in r5/6/7).
// Own h-half via LDS + barrier; peer 8KB half dual-posted (sc0 local L2 +
// sc0sc1 MALL mirror), consumer: 8 cached sc0 probes then sc1 fallback.
// Tags in every word + parity dbuf => correct on ANY XCD mapping.

typedef unsigned int u32;
typedef unsigned long long u64;
typedef unsigned short u16;

typedef _Float16 v8h __attribute__((ext_vector_type(8)));
typedef float    v4f __attribute__((ext_vector_type(4)));
typedef u32      v4u __attribute__((ext_vector_type(4)));

union H8 { v8h v; u64 q[2]; v4u u4; u32 d[4]; _Float16 h[8]; u16 s[8]; };

#define TAG(sid) (0x4000u + (u32)(sid))

// ws layout (u32 units): Lbuf [g][p][3 slots][16][128]; Mbuf same at +98304.
static __device__ __forceinline__ u32* lbufp(u32* ws, int g, int p, int slot){
  return ws + (u64)((g*2 + p)*3 + slot)*2048u;
}
static __device__ __forceinline__ u32* mbufp(u32* ws, int g, int p, int slot){
  return ws + 98304u + (u64)((g*2 + p)*3 + slot)*2048u;
}

static __device__ __forceinline__ float fsig(float x){
  return __builtin_amdgcn_rcpf(1.f + __builtin_amdgcn_exp2f(-1.4426950408889634f*x));
}
static __device__ __forceinline__ float ftanh(float x){
  return 1.f - 2.f*__builtin_amdgcn_rcpf(1.f + __builtin_amdgcn_exp2f(2.8853900817779268f*x));
}
static __device__ __forceinline__ u32 f2tag(float f, u32 tag){
  union{ _Float16 h; u16 b; } u; u.h = (_Float16)f;
  return (tag << 16) | (u32)u.b;
}

// Dual post: local-L2 copy (sc0) + MALL mirror (sc0 sc1). Fire-and-forget.
static __device__ __forceinline__ void post(u32* lp, u32* mp, u32 v){
  asm volatile("global_store_dword %0, %2, off sc0\n\t"
               "global_store_dword %1, %2, off sc0 sc1"
               :: "v"(lp), "v"(mp), "v"(v) : "memory");
}

// Batched 8-KB half-tile read (8 x dwordx4, one vmcnt drain).
static __device__ __forceinline__ void ld8_fast(const u32* p, v4u q[8]){
  asm volatile(
    "global_load_dwordx4 %0, %8, off sc0\n\t"
    "global_load_dwordx4 %1, %8, off offset:16 sc0\n\t"
    "global_load_dwordx4 %2, %8, off offset:128 sc0\n\t"
    "global_load_dwordx4 %3, %8, off offset:144 sc0\n\t"
    "global_load_dwordx4 %4, %8, off offset:256 sc0\n\t"
    "global_load_dwordx4 %5, %8, off offset:272 sc0\n\t"
    "global_load_dwordx4 %6, %8, off offset:384 sc0\n\t"
    "global_load_dwordx4 %7, %8, off offset:400 sc0\n\t"
    "s_waitcnt vmcnt(0)"
    : "=v"(q[0]), "=v"(q[1]), "=v"(q[2]), "=v"(q[3]),
      "=v"(q[4]), "=v"(q[5]), "=v"(q[6]), "=v"(q[7])
    : "v"(p) : "memory");
}
static __device__ __forceinline__ void ld8_slow(const u32* p, v4u q[8]){
  asm volatile(
    "global_load_dwordx4 %0, %8, off sc0 sc1\n\t"
    "global_load_dwordx4 %1, %8, off offset:16 sc0 sc1\n\t"
    "global_load_dwordx4 %2, %8, off offset:128 sc0 sc1\n\t"
    "global_load_dwordx4 %3, %8, off offset:144 sc0 sc1\n\t"
    "global_load_dwordx4 %4, %8, off offset:256 sc0 sc1\n\t"
    "global_load_dwordx4 %5, %8, off offset:272 sc0 sc1\n\t"
    "global_load_dwordx4 %6, %8, off offset:384 sc0 sc1\n\t"
    "global_load_dwordx4 %7, %8, off offset:400 sc0 sc1\n\t"
    "s_waitcnt vmcnt(0)"
    : "=v"(q[0]), "=v"(q[1]), "=v"(q[2]), "=v"(q[3]),
      "=v"(q[4]), "=v"(q[5]), "=v"(q[6]), "=v"(q[7])
    : "v"(p) : "memory");
}

static __device__ __forceinline__ bool tags_ok(const v4u q[8], u32 tm){
  u32 bad = 0;
  #pragma unroll
  for (int i = 0; i < 8; ++i)
    #pragma unroll
    for (int j = 0; j < 4; ++j) bad |= (q[i][j] ^ tm);
  return __all((bad & 0xFFFF0000u) == 0);
}
static __device__ __forceinline__ void pack8(const v4u q[8], H8 A[4]){
  #pragma unroll
  for (int k = 0; k < 4; ++k){
    const v4u a = q[2*k], b = q[2*k+1];
    A[k].d[0] = (a[0] & 0xFFFFu) | (a[1] << 16);
    A[k].d[1] = (a[2] & 0xFFFFu) | (a[3] << 16);
    A[k].d[2] = (b[0] & 0xFFFFu) | (b[1] << 16);
    A[k].d[3] = (b[2] & 0xFFFFu) | (b[3] << 16);
  }
}

// Poll the peer 16x128 tagged tile: 8 cached probes, then sc1 mirror loop.
static __device__ __forceinline__ void read_peer(const u32* lb, const u32* mb,
                                                 u32 tag, int c, int quad, H8 A[4]){
  const int off = c*128 + quad*8;
  const u32 tm = tag << 16;
  v4u q[8];
  #pragma unroll 1
  for (int a = 0; a < 8; ++a){
    ld8_fast(lb + off, q);
    if (tags_ok(q, tm)){ pack8(q, A); return; }
  }
  #pragma unroll 1
  for(;;){
    ld8_slow(mb + off, q);
    if (tags_ok(q, tm)){ pack8(q, A); return; }
    __builtin_amdgcn_s_sleep(1);
  }
}

// 4x11 B-fragments, K-slot order: 0-2 input (88 pad 96), 3-6 OWN Whh half
// (cols 128p..), 7-10 PEER half (cols 128(1-p)..). p only in addresses.
static __device__ __forceinline__ void build_Bw(v8h Bw[4][11], const float* Wih,
                                                const float* Whh, int wcolc,
                                                int quad, int p){
  #pragma unroll
  for (int nt = 0; nt < 4; ++nt){
    const int n = nt*256 + wcolc;
    #pragma unroll
    for (int kt = 0; kt < 11; ++kt){
      H8 a;
      #pragma unroll
      for (int j = 0; j < 8; ++j){
        float v;
        if (kt < 3){
          const int k = kt*32 + quad*8 + j;
          v = (k < 88) ? Wih[n*88 + k] : 0.f;
        } else if (kt < 7){
          const int k = 128*p + (kt-3)*32 + quad*8 + j;
          v = Whh[n*256 + k];
        } else {
          const int k = 128*(1-p) + (kt-7)*32 + quad*8 + j;
          v = Whh[n*256 + k];
        }
        a.h[j] = (_Float16)v;
      }
      Bw[nt][kt] = a.v;
    }
  }
}

__global__ __launch_bounds__(512, 1) void lstm_ae(
    const float* __restrict__ x,
    const float* __restrict__ Wih_e, const float* __restrict__ Whh_e,
    const float* __restrict__ bih_e, const float* __restrict__ bhh_e,
    const float* __restrict__ Wih_d, const float* __restrict__ Whh_d,
    const float* __restrict__ bih_d, const float* __restrict__ bhh_d,
    const float* __restrict__ W_lat, const float* __restrict__ b_lat,
    const float* __restrict__ W_decinit, const float* __restrict__ b_decinit,
    const float* __restrict__ W_out, const float* __restrict__ b_out,
    float* __restrict__ dout, char* __restrict__ ws)
{
  const int tid = (int)threadIdx.x;
  const int v = tid >> 6, l = tid & 63;
  const int c = l & 15, quad = (l >> 4) & 3;
  const int g = (int)blockIdx.x & 7, p = (int)blockIdx.x >> 3;
  const int wcolc = p*128 + v*16 + c;       // absolute gate/h column
  const int lcol  = v*16 + c;               // column within own half

  u32* wsu = (u32*)ws;

  __shared__ v4u      woutlds[3072];                 // 48 KB W_out B-frags
  __shared__ alignas(16) _Float16 hlds[2][16][136];  // own-half h dbuf (pad 8)
  __shared__ alignas(16) _Float16 zlds[16][136];
  __shared__ alignas(16) _Float16 predlds[16][104];

  // ---- prologue: W_out -> LDS, K-slots own-first (wave v: frags 6v..6v+6) --
  #pragma unroll
  for (int fi = 0; fi < 6; ++fi){
    const int fid = v*6 + fi, nt = fid >> 3, kt = fid & 7;
    const int n = nt*16 + c;
    const int k0 = ((kt < 4) ? 128*p : 128*(1-p)) + (kt & 3)*32 + quad*8;
    H8 a;
    #pragma unroll
    for (int j = 0; j < 8; ++j){
      float vv = (n < 88) ? W_out[n*256 + k0 + j] : 0.f;
      a.h[j] = (_Float16)vv;
    }
    woutlds[fid*64 + l] = a.u4;
  }

  v8h Bw[4][11];
  build_Bw(Bw, Wih_e, Whh_e, wcolc, quad, p);
  float be[4];
  #pragma unroll
  for (int nt = 0; nt < 4; ++nt){ const int n = nt*256 + wcolc; be[nt] = bih_e[n] + bhh_e[n]; }

  float cst[4] = {0.f, 0.f, 0.f, 0.f};
  __syncthreads();

  // ================= encoder =================
  #pragma unroll 1
  for (int t = 0; t < 1024; ++t){
    H8 Ax[3];
    {
      const float* xb = x + ((u64)(g*16 + c)*1024u + (u64)t)*88u;
      #pragma unroll
      for (int kt = 0; kt < 3; ++kt){
        const int k0 = kt*32 + quad*8;
        if (kt == 2 && quad == 3){ Ax[kt].q[0] = 0; Ax[kt].q[1] = 0; }
        else {
          v4f f0 = *(const v4f*)(xb + k0);
          v4f f1 = *(const v4f*)(xb + k0 + 4);
          #pragma unroll
          for (int j = 0; j < 4; ++j){ Ax[kt].h[j] = (_Float16)f0[j]; Ax[kt].h[j+4] = (_Float16)f1[j]; }
        }
      }
    }

    v4f acc[4];
    #pragma unroll
    for (int nt = 0; nt < 4; ++nt) acc[nt] = (v4f){0.f,0.f,0.f,0.f};
    #pragma unroll
    for (int kt = 0; kt < 3; ++kt)
      #pragma unroll
      for (int nt = 0; nt < 4; ++nt)
        acc[nt] = __builtin_amdgcn_mfma_f32_16x16x32_f16(Ax[kt].v, Bw[nt][kt], acc[nt], 0, 0, 0);

    if (t > 0){
      const int sl = (t-1) & 1;
      H8 Aho[4];
      const _Float16* hr = &hlds[sl][c][0];
      #pragma unroll
      for (int j = 0; j < 4; ++j) Aho[j].u4 = *(const v4u*)(hr + 32*j + quad*8);
      #pragma unroll
      for (int j = 0; j < 4; ++j)
        #pragma unroll
        for (int nt = 0; nt < 4; ++nt)
          acc[nt] = __builtin_amdgcn_mfma_f32_16x16x32_f16(Aho[j].v, Bw[nt][3 + j], acc[nt], 0, 0, 0);

      H8 Ahp[4];
      read_peer(lbufp(wsu,g,1-p,sl), mbufp(wsu,g,1-p,sl), TAG(t-1), c, quad, Ahp);
      #pragma unroll
      for (int j = 0; j < 4; ++j)
        #pragma unroll
        for (int nt = 0; nt < 4; ++nt)
          acc[nt] = __builtin_amdgcn_mfma_f32_16x16x32_f16(Ahp[j].v, Bw[nt][7 + j], acc[nt], 0, 0, 0);
    }

    u32* Lw = lbufp(wsu, g, p, t & 1);
    u32* Mw = mbufp(wsu, g, p, t & 1);
    const u32 tg = TAG(t);
    #pragma unroll
    for (int r = 0; r < 4; ++r){
      const float gi = acc[0][r] + be[0];
      const float gf = acc[1][r] + be[1];
      const float gg = acc[2][r] + be[2];
      const float go = acc[3][r] + be[3];
      const float cn = fsig(gf)*cst[r] + fsig(gi)*ftanh(gg);
      cst[r] = cn;
      const float hn = fsig(go)*ftanh(cn);
      const int m = quad*4 + r;
      hlds[t & 1][m][lcol] = (_Float16)hn;
      const int off = m*128 + lcol;
      post(Lw + off, Mw + off, f2tag(hn, tg));
    }
    __syncthreads();
  }

  // ---- latent: z = h_n @ W_lat.T + b_lat (each wave: one 16-col z-tile) ----
  {
    H8 Aho[4], Ahp[4];
    const _Float16* hr = &hlds[1][c][0];
    #pragma unroll
    for (int j = 0; j < 4; ++j) Aho[j].u4 = *(const v4u*)(hr + 32*j + quad*8);
    read_peer(lbufp(wsu,g,1-p,1), mbufp(wsu,g,1-p,1), TAG(1023), c, quad, Ahp);

    const int zn = v*16 + c;   // z column, < 128
    v4f zacc = (v4f){0.f,0.f,0.f,0.f};
    #pragma unroll
    for (int k = 0; k < 4; ++k){          // own half, K = 128p + 32k ..
      H8 b;
      const int k0 = 128*p + k*32 + quad*8;
      v4f f0 = *(const v4f*)(W_lat + zn*256 + k0);
      v4f f1 = *(const v4f*)(W_lat + zn*256 + k0 + 4);
      #pragma unroll
      for (int j = 0; j < 4; ++j){ b.h[j] = (_Float16)f0[j]; b.h[j+4] = (_Float16)f1[j]; }
      zacc = __builtin_amdgcn_mfma_f32_16x16x32_f16(Aho[k].v, b.v, zacc, 0, 0, 0);
    }
    #pragma unroll
    for (int k = 0; k < 4; ++k){          // peer half
      H8 b;
      const int k0 = 128*(1-p) + k*32 + quad*8;
      v4f f0 = *(const v4f*)(W_lat + zn*256 + k0);
      v4f f1 = *(const v4f*)(W_lat + zn*256 + k0 + 4);
      #pragma unroll
      for (int j = 0; j < 4; ++j){ b.h[j] = (_Float16)f0[j]; b.h[j+4] = (_Float16)f1[j]; }
      zacc = __builtin_amdgcn_mfma_f32_16x16x32_f16(Ahp[k].v, b.v, zacc, 0, 0, 0);
    }
    const float bl = b_lat[zn];
    #pragma unroll
    for (int r = 0; r < 4; ++r){
      const int m = quad*4 + r;
      const float zv = zacc[r] + bl;
      if (p == 0)
        __builtin_nontemporal_store(zv, dout + 11534336u + (u64)(g*16 + m)*128u + zn);
      zlds[m][zn] = (_Float16)zv;
    }
  }

  // ---- switch weights to decoder ----
  build_Bw(Bw, Wih_d, Whh_d, wcolc, quad, p);
  float bd[4];
  #pragma unroll
  for (int nt = 0; nt < 4; ++nt){ const int n = nt*256 + wcolc; bd[nt] = bih_d[n] + bhh_d[n]; }
  const float bov = (v < 6 && (v*16 + c) < 88) ? b_out[v*16 + c] : 0.f;
  __syncthreads();

  // ---- decoder init: h0 = z @ W_decinit.T + b_decinit ----
  {
    H8 Az[4];
    #pragma unroll
    for (int kt = 0; kt < 4; ++kt)
      Az[kt].u4 = *(const v4u*)(&zlds[c][kt*32 + quad*8]);
    v4f da = (v4f){0.f,0.f,0.f,0.f};
    #pragma unroll
    for (int kt = 0; kt < 4; ++kt){
      H8 b;
      const int k0 = kt*32 + quad*8;
      v4f f0 = *(const v4f*)(W_decinit + wcolc*128 + k0);
      v4f f1 = *(const v4f*)(W_decinit + wcolc*128 + k0 + 4);
      #pragma unroll
      for (int j = 0; j < 4; ++j){ b.h[j] = (_Float16)f0[j]; b.h[j+4] = (_Float16)f1[j]; }
      da = __builtin_amdgcn_mfma_f32_16x16x32_f16(Az[kt].v, b.v, da, 0, 0, 0);
    }
    const float bdi = b_decinit[wcolc];
    u32* Lw = lbufp(wsu, g, p, 2);
    u32* Mw = mbufp(wsu, g, p, 2);
    #pragma unroll
    for (int r = 0; r < 4; ++r){
      const int m = quad*4 + r;
      const float hv = da[r] + bdi;
      hlds[1][m][lcol] = (_Float16)hv;
      const int off = m*128 + lcol;
      post(Lw + off, Mw + off, f2tag(hv, TAG(1025)));
    }
  }
  #pragma unroll
  for (int r = 0; r < 4; ++r) cst[r] = 0.f;
  __syncthreads();

  // ================= decoder =================
  #pragma unroll 1
  for (int t = 0; t < 1024; ++t){
    const int sl = (t-1) & 1;                 // LDS slot of h(t-1) (t=0 -> 1)
    const int gsl = (t == 0) ? 2 : sl;        // global slot (h0 lives in 2)
    H8 Aho[4], Ahp[4];
    const _Float16* hr = &hlds[sl][c][0];
    #pragma unroll
    for (int j = 0; j < 4; ++j) Aho[j].u4 = *(const v4u*)(hr + 32*j + quad*8);
    read_peer(lbufp(wsu,g,1-p,gsl), mbufp(wsu,g,1-p,gsl), TAG(1025 + t), c, quad, Ahp);

    if (t > 0 && v < 6){
      v4f pacc = (v4f){0.f,0.f,0.f,0.f};
      #pragma unroll
      for (int k = 0; k < 4; ++k){          // own-half K slots 0-3
        H8 b; b.u4 = woutlds[(v*8 + k)*64 + l];
        pacc = __builtin_amdgcn_mfma_f32_16x16x32_f16(Aho[k].v, b.v, pacc, 0, 0, 0);
      }
      #pragma unroll
      for (int k = 0; k < 4; ++k){          // peer-half K slots 4-7
        H8 b; b.u4 = woutlds[(v*8 + 4 + k)*64 + l];
        pacc = __builtin_amdgcn_mfma_f32_16x16x32_f16(Ahp[k].v, b.v, pacc, 0, 0, 0);
      }
      const int col = v*16 + c;
      #pragma unroll
      for (int r = 0; r < 4; ++r){
        const float pv = fsig(pacc[r] + bov);
        const int m = quad*4 + r;
        predlds[m][col] = (_Float16)pv;
        if (col < 88)
          __builtin_nontemporal_store(pv,
            dout + ((u64)(g*16 + m)*1024u + (u64)(t-1))*88u + col);
      }
    }
    __syncthreads();

    H8 Ap[3];
    if (t == 0){
      #pragma unroll
      for (int kt = 0; kt < 3; ++kt){ Ap[kt].q[0] = 0; Ap[kt].q[1] = 0; }
    } else {
      #pragma unroll
      for (int kt = 0; kt < 3; ++kt)
        Ap[kt].u4 = *(const v4u*)(&predlds[c][kt*32 + quad*8]);
    }

    v4f acc[4];
    #pragma unroll
    for (int nt = 0; nt < 4; ++nt) acc[nt] = (v4f){0.f,0.f,0.f,0.f};
    #pragma unroll
    for (int kt = 0; kt < 3; ++kt)
      #pragma unroll
      for (int nt = 0; nt < 4; ++nt)
        acc[nt] = __builtin_amdgcn_mfma_f32_16x16x32_f16(Ap[kt].v, Bw[nt][kt], acc[nt], 0, 0, 0);
    #pragma unroll
    for (int j = 0; j < 4; ++j)
      #pragma unroll
      for (int nt = 0; nt < 4; ++nt)
        acc[nt] = __builtin_amdgcn_mfma_f32_16x16x32_f16(Aho[j].v, Bw[nt][3 + j], acc[nt], 0, 0, 0);
    #pragma unroll
    for (int j = 0; j < 4; ++j)
      #pragma unroll
      for (int nt = 0; nt < 4; ++nt)
        acc[nt] = __builtin_amdgcn_mfma_f32_16x16x32_f16(Ahp[j].v, Bw[nt][7 + j], acc[nt], 0, 0, 0);

    u32* Lw = lbufp(wsu, g, p, t & 1);
    u32* Mw = mbufp(wsu, g, p, t & 1);
    const u32 wtg = TAG(1026 + t);
    #pragma unroll
    for (int r = 0; r < 4; ++r){
      const float gi = acc[0][r] + bd[0];
      const float gf = acc[1][r] + bd[1];
      const float gg = acc[2][r] + bd[2];
      const float go = acc[3][r] + bd[3];
      const float cn = fsig(gf)*cst[r] + fsig(gi)*ftanh(gg);
      cst[r] = cn;
      const float hn = fsig(go)*ftanh(cn);
      const int m = quad*4 + r;
      hlds[t & 1][m][lcol] = (_Float16)hn;
      const int off = m*128 + lcol;
      post(Lw + off, Mw + off, f2tag(hn, wtg));
    }
    __syncthreads();
  }

  // ---- tail: pred(1023) -> output row 1023 ----
  {
    H8 Aho[4], Ahp[4];
    const _Float16* hr = &hlds[1][c][0];
    #pragma unroll
    for (int j = 0; j < 4; ++j) Aho[j].u4 = *(const v4u*)(hr + 32*j + quad*8);
    read_peer(lbufp(wsu,g,1-p,1), mbufp(wsu,g,1-p,1), TAG(2049), c, quad, Ahp);
    if (v < 6){
      v4f pacc = (v4f){0.f,0.f,0.f,0.f};
      #pragma unroll
      for (int k = 0; k < 4; ++k){
        H8 b; b.u4 = woutlds[(v*8 + k)*64 + l];
        pacc = __builtin_amdgcn_mfma_f32_16x16x32_f16(Aho[k].v, b.v, pacc, 0, 0, 0);
      }
      #pragma unroll
      for (int k = 0; k < 4; ++k){
        H8 b; b.u4 = woutlds[(v*8 + 4 + k)*64 + l];
        pacc = __builtin_amdgcn_mfma_f32_16x16x32_f16(Ahp[k].v, b.v, pacc, 0, 0, 0);
      }
      const int col = v*16 + c;
      if (col < 88){
        #pragma unroll
        for (int r = 0; r < 4; ++r){
          const float pv = fsig(pacc[r] + bov);
          const int m = quad*4 + r;
          __builtin_nontemporal_store(pv,
            dout + ((u64)(g*16 + m)*1024u + 1023u)*88u + col);
        }
      }
    }
  }
}

extern "C" void kernel_launch(void* const* d_in, const int* in_sizes, int n_in,
                              void* d_out, int out_size, void* d_ws, size_t ws_size,
                              hipStream_t stream){
  (void)in_sizes; (void)n_in; (void)out_size; (void)ws_size;
  hipLaunchKernelGGL(lstm_ae, dim3(16), dim3(512), 0, stream,
    (const float*)d_in[0],  (const float*)d_in[1],  (const float*)d_in[2],
    (const float*)d_in[3],  (const float*)d_in[4],  (const float*)d_in[5],
    (const float*)d_in[6],  (const float*)d_in[7],  (const float*)d_in[8],
    (const float*)d_in[9],  (const float*)d_in[10], (const float*)d_in[11],
    (const float*)d_in[12], (const float*)d_in[13], (const float*)d_in[14],
    (float*)d_out, (char*)d_ws);
}